// Round 10
// baseline (1272.719 us; speedup 1.0000x reference)
//
#include <hip/hip_runtime.h>
#include <hip/hip_bf16.h>
#include <math.h>

#define NEG_SLOPE 0.2f
#define ECLAMP 30.0f
#define HCLAMP 1.0e4f
#define NBMAX 1024      // max buckets (N <= 131072)

typedef short v8s __attribute__((ext_vector_type(8)));
typedef float v4f __attribute__((ext_vector_type(4)));

__device__ __forceinline__ float bf2f(__hip_bfloat16 v) { return __bfloat162float(v); }
__device__ __forceinline__ __hip_bfloat16 f2bf(float v) { return __float2bfloat16(v); }
__device__ __forceinline__ float sane(float v)   { return fminf(fmaxf(v, -HCLAMP), HCLAMP); }
__device__ __forceinline__ float eclampf(float v){ return fminf(fmaxf(v, -ECLAMP), ECLAMP); }

__device__ __forceinline__ float ldany(int isf32, const void* p, int i) {
    return isf32 ? ((const float*)p)[i] : bf2f(((const __hip_bfloat16*)p)[i]);
}
__device__ __forceinline__ int ldidx(int is64, const void* p, long long i) {
    return is64 ? (int)((const long long*)p)[i] : ((const int*)p)[i];
}
__device__ __forceinline__ v8s ld8(const __hip_bfloat16* p) { return *(const v8s*)p; }

__device__ __forceinline__ float ewgt(float e) {
    e = e > 0.f ? e : NEG_SLOPE * e;
    return __expf(eclampf(e));
}

// ---------- dtype probe ----------
__global__ void k_probe(const unsigned* __restrict__ xw, int nw_safe,
                        const unsigned* __restrict__ ew, int* __restrict__ flags) {
    __shared__ int cnt[2];
    int t = threadIdx.x;
    if (t < 2) cnt[t] = 0;
    __syncthreads();
    unsigned w = xw[(unsigned)(t * 9973) % (unsigned)nw_safe];
    unsigned lo = w & 0xffffu;
    unsigned exp = (lo >> 7) & 0xffu;
    if (lo != 0u && (exp < 90u || exp > 160u)) atomicAdd(&cnt[0], 1);
    if (ew[2 * t + 1] == 0u) atomicAdd(&cnt[1], 1);
    __syncthreads();
    if (t == 0) { flags[0] = (2 * cnt[0] > 256) ? 1 : 0; flags[1] = (cnt[1] >= 200) ? 1 : 0; }
}

// ---------- params ----------
__global__ void k_params(const int* __restrict__ flags,
                         const void* W0, const void* sW0, const void* as0, const void* ad0,
                         const void* b0, const void* sb0, const void* W1, const void* sW1,
                         const void* as1, const void* ad1, const void* b1, const void* sb1,
                         float* __restrict__ Pf, __hip_bfloat16* __restrict__ Wg) {
    int f = flags[0];
    int t = blockIdx.x * blockDim.x + threadIdx.x;
    int T = gridDim.x * blockDim.x;
    for (int i = t; i < 8192; i += T) {
        int n = i >> 7, k = i & 127;
        Wg[i]        = f2bf(ldany(f, W0,  k * 64 + n));
        Wg[8192 + i] = f2bf(ldany(f, sW0, k * 64 + n));
    }
    for (int i = t; i < 2048; i += T) {
        int n = i >> 6, k = i & 63;
        Wg[16384 + i] = f2bf(ldany(f, W1,  k * 32 + n));
        Wg[18432 + i] = f2bf(ldany(f, sW1, k * 32 + n));
    }
    if (t < 64) {
        Pf[t]       = ldany(f, as0, t);
        Pf[64 + t]  = ldany(f, ad0, t);
        Pf[128 + t] = ldany(f, b0, t) + ldany(f, sb0, t);
    }
    if (t < 32) {
        Pf[192 + t] = ldany(f, as1, t);
        Pf[224 + t] = ldany(f, ad1, t);
        Pf[256 + t] = ldany(f, b1, t) + ldany(f, sb1, t);
    }
}

__global__ void k_zero(int* __restrict__ p, int n) {
    int i = blockIdx.x * blockDim.x + threadIdx.x;
    if (i < n) p[i] = 0;
}

// ---------- bucket counting: LDS hist, one global atomic per (block,bucket) ----------
__global__ __launch_bounds__(256) void k_bcount(
    const void* __restrict__ ei, const int* __restrict__ flags,
    int E, int N, int NB, int* __restrict__ bsize) {
    __shared__ int hist[NBMAX];
    int t = threadIdx.x;
    for (int i = t; i < NB; i += 256) hist[i] = 0;
    __syncthreads();
    int f = flags[1];
    long long base = (long long)blockIdx.x * 4096;
#pragma unroll
    for (int k = 0; k < 16; k++) {
        long long i = base + k * 256 + t;
        if (i < E) {
            int d = ldidx(f, ei, (long long)E + i);
            if ((unsigned)d < (unsigned)N) atomicAdd(&hist[d >> 7], 1);
        }
    }
    __syncthreads();
    for (int i = t; i < NB; i += 256)
        if (hist[i]) atomicAdd(&bsize[i], hist[i]);
}

// ---------- bucket base scan (NB <= 1024), also inits bcur ----------
__global__ void k_bbase(const int* __restrict__ bsize, int NB,
                        int* __restrict__ bbase, int* __restrict__ bcur) {
    __shared__ int sh[1024];
    int t = threadIdx.x;
    int v = (t < NB) ? bsize[t] : 0;
    sh[t] = v;
    __syncthreads();
    for (int off = 1; off < 1024; off <<= 1) {
        int xv = (t >= off) ? sh[t - off] : 0;
        __syncthreads();
        sh[t] += xv;
        __syncthreads();
    }
    if (t < NB) { int e = sh[t] - v; bbase[t] = e; bcur[t] = e; }
}

// ---------- bucket scatter: LDS hist + per-block reservation + in-LDS sort ----------
// edges packed: word = src | ((dst&127)<<24); dst = bucket*128 + (word>>24)&127
__global__ __launch_bounds__(1024) void k_bscatter(
    const void* __restrict__ ei, const int* __restrict__ flags,
    int E, int N, int NB, int* __restrict__ bcur, int* __restrict__ ebuk) {
    __shared__ int hist[NBMAX];
    __shared__ int lbase[NBMAX];
    __shared__ int gbase[NBMAX];
    __shared__ int staged[4096];
    __shared__ short bktid[4096];
    __shared__ int tot;
    int t = threadIdx.x;
    for (int i = t; i < NB; i += 1024) hist[i] = 0;
    __syncthreads();
    int f = flags[1];
    long long base = (long long)blockIdx.x * 4096;
    int myW[4], myB[4];
#pragma unroll
    for (int k = 0; k < 4; k++) {
        long long i = base + k * 1024 + t;
        myB[k] = -1;
        if (i < E) {
            int s = ldidx(f, ei, i);
            int d = ldidx(f, ei, (long long)E + i);
            if ((unsigned)s < (unsigned)N && (unsigned)d < (unsigned)N) {
                myB[k] = d >> 7;
                myW[k] = s | ((d & 127) << 24);
                atomicAdd(&hist[myB[k]], 1);
            }
        }
    }
    __syncthreads();
    // inclusive scan of hist into lbase
    if (t < NB) lbase[t] = hist[t];
    __syncthreads();
    for (int off = 1; off < NBMAX; off <<= 1) {
        int xv = (t >= off && t < NB) ? lbase[t - off] : 0;
        __syncthreads();
        if (t < NB) lbase[t] += xv;
        __syncthreads();
    }
    if (t < NB) {
        int h = hist[t];
        lbase[t] -= h;                                   // exclusive
        gbase[t] = h ? atomicAdd(&bcur[t], h) : 0;       // global reservation
        hist[t] = 0;                                     // reset for rank pass
    }
    if (t == 0) tot = 0;
    __syncthreads();
    // rank & stage (sorted by bucket within block)
#pragma unroll
    for (int k = 0; k < 4; k++) {
        if (myB[k] >= 0) {
            int r = atomicAdd(&hist[myB[k]], 1);
            int slot = lbase[myB[k]] + r;
            staged[slot] = myW[k];
            bktid[slot] = (short)myB[k];
            atomicAdd(&tot, 1);
        }
    }
    __syncthreads();
    int total = tot;
    // coalesced-run writeout
    for (int i = t; i < total; i += 1024) {
        int b = (int)bktid[i];
        ebuk[gbase[b] + (i - lbase[b])] = staged[i];
    }
}

// ---------- layer 0 transform: MFMA 16x16x32 bf16 ----------
__global__ __launch_bounds__(256) void k_l0(
    const void* __restrict__ x, const int* __restrict__ flags,
    const float* __restrict__ Pf, const __hip_bfloat16* __restrict__ Wg, int N,
    __hip_bfloat16* __restrict__ h0, __hip_bfloat16* __restrict__ skip0,
    float* __restrict__ ssrc, float* __restrict__ sdst) {
    __shared__ __hip_bfloat16 sm[26112];
    __hip_bfloat16* xs  = sm;
    __hip_bfloat16* wt0 = sm + 8704;
    __hip_bfloat16* wts = sm + 17408;
    int tid = threadIdx.x;
    int f = flags[0];
    int tile = blockIdx.x * 64;

    for (int i = tid * 4; i < 8192; i += 1024) {
        int r = i >> 7, k = i & 127;
        __hip_bfloat16* d0 = &wt0[r * 136 + k];
        __hip_bfloat16* d1 = &wts[r * 136 + k];
#pragma unroll
        for (int u = 0; u < 4; u++) { d0[u] = Wg[i + u]; d1[u] = Wg[8192 + i + u]; }
    }
    for (int i = tid * 4; i < 8192; i += 1024) {
        int r = i >> 7, k = i & 127;
        int g = tile + r; if (g >= N) g = N - 1;
        __hip_bfloat16* dx = &xs[r * 136 + k];
        if (f) {
            const float* xp = (const float*)x + (size_t)g * 128 + k;
#pragma unroll
            for (int u = 0; u < 4; u++) dx[u] = f2bf(xp[u]);
        } else {
            const __hip_bfloat16* xp = (const __hip_bfloat16*)x + (size_t)g * 128 + k;
#pragma unroll
            for (int u = 0; u < 4; u++) dx[u] = xp[u];
        }
    }
    __syncthreads();

    int lane = tid & 63, w = tid >> 6;
    int n16 = lane & 15, quad = lane >> 4;
    v4f zf = {0.f, 0.f, 0.f, 0.f};
    v4f acc_h[4], acc_s[4];
#pragma unroll
    for (int t = 0; t < 4; t++) { acc_h[t] = zf; acc_s[t] = zf; }

    int arow = (w << 4) + n16;
#pragma unroll
    for (int s = 0; s < 4; s++) {
        v8s a = ld8(&xs[arow * 136 + s * 32 + (quad << 3)]);
#pragma unroll
        for (int t = 0; t < 4; t++) {
            v8s bh = ld8(&wt0[(t * 16 + n16) * 136 + s * 32 + (quad << 3)]);
            acc_h[t] = __builtin_amdgcn_mfma_f32_16x16x32_bf16(a, bh, acc_h[t], 0, 0, 0);
            v8s bs = ld8(&wts[(t * 16 + n16) * 136 + s * 32 + (quad << 3)]);
            acc_s[t] = __builtin_amdgcn_mfma_f32_16x16x32_bf16(a, bs, acc_s[t], 0, 0, 0);
        }
    }

    int mbase = tile + (w << 4) + (quad << 2);
    float ps[4] = {0, 0, 0, 0}, pd[4] = {0, 0, 0, 0};
#pragma unroll
    for (int t = 0; t < 4; t++) {
        int ch = t * 16 + n16;
        float av = Pf[ch];
        float dv = Pf[64 + ch];
        float bv = Pf[128 + ch];
#pragma unroll
        for (int r = 0; r < 4; r++) {
            float hv = sane(acc_h[t][r]);
            float sv = sane(acc_s[t][r] + bv);
            int node = mbase + r;
            if (node < N) {
                h0[(size_t)node * 64 + ch] = f2bf(hv);
                skip0[(size_t)node * 64 + ch] = f2bf(sv);
            }
            ps[r] += hv * av;
            pd[r] += hv * dv;
        }
    }
#pragma unroll
    for (int m = 1; m <= 8; m <<= 1) {
#pragma unroll
        for (int r = 0; r < 4; r++) {
            ps[r] += __shfl_xor(ps[r], m, 64);
            pd[r] += __shfl_xor(pd[r], m, 64);
        }
    }
    if (n16 == 0) {
#pragma unroll
        for (int r = 0; r < 4; r++) {
            int node = mbase + r;
            if (node < N) { ssrc[node] = sane(ps[r]); sdst[node] = sane(pd[r]); }
        }
    }
}

// ---------- layer 0 bucket aggregation (LDS accumulate) + self + skip + ELU ----------
__global__ __launch_bounds__(256) void k_agg0(
    const int* __restrict__ bbase, const int* __restrict__ bsize,
    const int* __restrict__ ebuk,
    const float* __restrict__ ssrc, const float* __restrict__ sdst,
    const __hip_bfloat16* __restrict__ h0,
    int N, __hip_bfloat16* __restrict__ skip0_hact) {
    __shared__ float acc[8192];
    __shared__ float den[128];
    int tid = threadIdx.x;
    int b = blockIdx.x;
    int tile = b << 7;
    for (int i = tid; i < 8192; i += 256) acc[i] = 0.f;
    if (tid < 128) den[tid] = 0.f;
    __syncthreads();
    int beg = bbase[b], end = beg + bsize[b];
    int wave = tid >> 6, lane = tid & 63;
    int j = beg + wave;
    for (; j + 4 < end; j += 8) {
        int w0 = ebuk[j], w1 = ebuk[j + 4];
        int s0 = w0 & 0xFFFFFF, d0 = (w0 >> 24) & 127;
        int s1 = w1 & 0xFFFFFF, d1 = (w1 >> 24) & 127;
        float e0 = ewgt(ssrc[s0] + sdst[tile + d0]);
        float e1 = ewgt(ssrc[s1] + sdst[tile + d1]);
        float g0 = bf2f(h0[(size_t)s0 * 64 + lane]);
        float g1 = bf2f(h0[(size_t)s1 * 64 + lane]);
        atomicAdd(&acc[(d0 << 6) + lane], e0 * g0);
        atomicAdd(&acc[(d1 << 6) + lane], e1 * g1);
        if (lane == 0) { atomicAdd(&den[d0], e0); atomicAdd(&den[d1], e1); }
    }
    for (; j < end; j += 4) {
        int w0 = ebuk[j];
        int s0 = w0 & 0xFFFFFF, d0 = (w0 >> 24) & 127;
        float e0 = ewgt(ssrc[s0] + sdst[tile + d0]);
        float g0 = bf2f(h0[(size_t)s0 * 64 + lane]);
        atomicAdd(&acc[(d0 << 6) + lane], e0 * g0);
        if (lane == 0) atomicAdd(&den[d0], e0);
    }
    __syncthreads();
    for (int i = tid; i < 8192; i += 256) {
        int nn = i >> 6, ch = i & 63;
        int n = tile + nn;
        if (n >= N) continue;
        float wself = ewgt(ssrc[n] + sdst[n]);
        float dtot = den[nn] + wself;
        float num = acc[i] + wself * bf2f(h0[(size_t)n * 64 + ch]);
        float v = sane(num / dtot + bf2f(skip0_hact[(size_t)n * 64 + ch]));
        v = v > 0.f ? v : (__expf(v) - 1.f);   // ELU
        skip0_hact[(size_t)n * 64 + ch] = f2bf(v);
    }
}

// ---------- layer 1 transform: MFMA, Fin=64, C=32 ----------
__global__ __launch_bounds__(256) void k_l1(
    const __hip_bfloat16* __restrict__ hact,
    const float* __restrict__ Pf, const __hip_bfloat16* __restrict__ Wg, int N,
    __hip_bfloat16* __restrict__ h1, __hip_bfloat16* __restrict__ skip1,
    float* __restrict__ ssrc, float* __restrict__ sdst) {
    __shared__ __hip_bfloat16 sm[9216];
    __hip_bfloat16* xs  = sm;
    __hip_bfloat16* wt1 = sm + 4608;
    __hip_bfloat16* ws1 = sm + 6912;
    int tid = threadIdx.x;
    int tile = blockIdx.x * 64;

    for (int i = tid * 4; i < 2048; i += 1024) {
        int r = i >> 6, k = i & 63;
        __hip_bfloat16* d0 = &wt1[r * 72 + k];
        __hip_bfloat16* d1 = &ws1[r * 72 + k];
#pragma unroll
        for (int u = 0; u < 4; u++) { d0[u] = Wg[16384 + i + u]; d1[u] = Wg[18432 + i + u]; }
    }
    for (int i = tid * 4; i < 4096; i += 1024) {
        int r = i >> 6, k = i & 63;
        int g = tile + r; if (g >= N) g = N - 1;
        __hip_bfloat16* dx = &xs[r * 72 + k];
        const __hip_bfloat16* xp = hact + (size_t)g * 64 + k;
#pragma unroll
        for (int u = 0; u < 4; u++) dx[u] = xp[u];
    }
    __syncthreads();

    int lane = tid & 63, w = tid >> 6;
    int n16 = lane & 15, quad = lane >> 4;
    v4f zf = {0.f, 0.f, 0.f, 0.f};
    v4f acc_h[2], acc_s[2];
#pragma unroll
    for (int t = 0; t < 2; t++) { acc_h[t] = zf; acc_s[t] = zf; }

    int arow = (w << 4) + n16;
#pragma unroll
    for (int s = 0; s < 2; s++) {
        v8s a = ld8(&xs[arow * 72 + s * 32 + (quad << 3)]);
#pragma unroll
        for (int t = 0; t < 2; t++) {
            v8s bh = ld8(&wt1[(t * 16 + n16) * 72 + s * 32 + (quad << 3)]);
            acc_h[t] = __builtin_amdgcn_mfma_f32_16x16x32_bf16(a, bh, acc_h[t], 0, 0, 0);
            v8s bs = ld8(&ws1[(t * 16 + n16) * 72 + s * 32 + (quad << 3)]);
            acc_s[t] = __builtin_amdgcn_mfma_f32_16x16x32_bf16(a, bs, acc_s[t], 0, 0, 0);
        }
    }

    int mbase = tile + (w << 4) + (quad << 2);
    float ps[4] = {0, 0, 0, 0}, pd[4] = {0, 0, 0, 0};
#pragma unroll
    for (int t = 0; t < 2; t++) {
        int ch = t * 16 + n16;
        float av = Pf[192 + ch];
        float dv = Pf[224 + ch];
        float bv = Pf[256 + ch];
#pragma unroll
        for (int r = 0; r < 4; r++) {
            float hv = sane(acc_h[t][r]);
            float sv = sane(acc_s[t][r] + bv);
            int node = mbase + r;
            if (node < N) {
                h1[(size_t)node * 32 + ch] = f2bf(hv);
                skip1[(size_t)node * 32 + ch] = f2bf(sv);
            }
            ps[r] += hv * av;
            pd[r] += hv * dv;
        }
    }
#pragma unroll
    for (int m = 1; m <= 8; m <<= 1) {
#pragma unroll
        for (int r = 0; r < 4; r++) {
            ps[r] += __shfl_xor(ps[r], m, 64);
            pd[r] += __shfl_xor(pd[r], m, 64);
        }
    }
    if (n16 == 0) {
#pragma unroll
        for (int r = 0; r < 4; r++) {
            int node = mbase + r;
            if (node < N) { ssrc[node] = sane(ps[r]); sdst[node] = sane(pd[r]); }
        }
    }
}

// ---------- layer 1 bucket aggregation + self + skip + log_softmax ----------
__global__ __launch_bounds__(256) void k_agg1(
    const int* __restrict__ bbase, const int* __restrict__ bsize,
    const int* __restrict__ ebuk,
    const float* __restrict__ ssrc, const float* __restrict__ sdst,
    const __hip_bfloat16* __restrict__ h1, const __hip_bfloat16* __restrict__ skip1,
    int N, float* __restrict__ out) {
    __shared__ float acc[4096];
    __shared__ float den[128];
    int tid = threadIdx.x;
    int b = blockIdx.x;
    int tile = b << 7;
    for (int i = tid; i < 4096; i += 256) acc[i] = 0.f;
    if (tid < 128) den[tid] = 0.f;
    __syncthreads();
    int beg = bbase[b], end = beg + bsize[b];
    int hw = tid >> 5, lane = tid & 31;
    int j = beg + hw;
    for (; j + 8 < end; j += 16) {
        int w0 = ebuk[j], w1 = ebuk[j + 8];
        int s0 = w0 & 0xFFFFFF, d0 = (w0 >> 24) & 127;
        int s1 = w1 & 0xFFFFFF, d1 = (w1 >> 24) & 127;
        float e0 = ewgt(ssrc[s0] + sdst[tile + d0]);
        float e1 = ewgt(ssrc[s1] + sdst[tile + d1]);
        float g0 = bf2f(h1[(size_t)s0 * 32 + lane]);
        float g1 = bf2f(h1[(size_t)s1 * 32 + lane]);
        atomicAdd(&acc[(d0 << 5) + lane], e0 * g0);
        atomicAdd(&acc[(d1 << 5) + lane], e1 * g1);
        if (lane == 0) { atomicAdd(&den[d0], e0); atomicAdd(&den[d1], e1); }
    }
    for (; j < end; j += 8) {
        int w0 = ebuk[j];
        int s0 = w0 & 0xFFFFFF, d0 = (w0 >> 24) & 127;
        float e0 = ewgt(ssrc[s0] + sdst[tile + d0]);
        float g0 = bf2f(h1[(size_t)s0 * 32 + lane]);
        atomicAdd(&acc[(d0 << 5) + lane], e0 * g0);
        if (lane == 0) atomicAdd(&den[d0], e0);
    }
    __syncthreads();
    for (int nn = hw; nn < 128; nn += 8) {
        int n = tile + nn;
        if (n >= N) continue;
        float wself = ewgt(ssrc[n] + sdst[n]);
        float dtot = den[nn] + wself;
        float num = acc[(nn << 5) + lane] + wself * bf2f(h1[(size_t)n * 32 + lane]);
        float o = sane(num / dtot + bf2f(skip1[(size_t)n * 32 + lane]));
        float m = o;
#pragma unroll
        for (int k = 16; k >= 1; k >>= 1) m = fmaxf(m, __shfl_xor(m, k, 32));
        float ex = __expf(o - m);
        float ssum = ex;
#pragma unroll
        for (int k = 16; k >= 1; k >>= 1) ssum += __shfl_xor(ssum, k, 32);
        float res = o - m - __logf(ssum);
        if (!isfinite(res)) res = 0.f;
        out[(size_t)n * 32 + lane] = res;
    }
}

__global__ void k_sentinel(float* __restrict__ out, int n, float val) {
    int i = blockIdx.x * blockDim.x + threadIdx.x;
    if (i < n) out[i] = val;
}

extern "C" void kernel_launch(void* const* d_in, const int* in_sizes, int n_in,
                              void* d_out, int out_size, void* d_ws, size_t ws_size,
                              hipStream_t stream) {
    const void* x  = d_in[0];
    const void* ei = d_in[1];
    float* out = (float*)d_out;

    int N = in_sizes[0] / 128;
    int E = in_sizes[1] / 2;
    int NB = (N + 127) >> 7;     // 128-node buckets

    char* ws = (char*)d_ws;
    size_t off = 0;
    auto alloc = [&](size_t bytes) -> char* {
        char* p = ws + off;
        off += (bytes + 255) & ~(size_t)255;
        return p;
    };
    int*   flags   = (int*)alloc(2 * 4);
    float* Pf      = (float*)alloc(288 * 4);
    __hip_bfloat16* Wg = (__hip_bfloat16*)alloc(20480 * 2);
    float* ssrc    = (float*)alloc((size_t)N * 4);
    float* sdst    = (float*)alloc((size_t)N * 4);
    int*   bsize   = (int*)alloc((size_t)NB * 4);
    int*   bbase   = (int*)alloc((size_t)NB * 4);
    int*   bcur    = (int*)alloc((size_t)NB * 4);
    int*   ebuk    = (int*)alloc((size_t)E * 4);
    __hip_bfloat16* h0    = (__hip_bfloat16*)alloc((size_t)N * 64 * 2); // -> h1+skip1
    __hip_bfloat16* skip0 = (__hip_bfloat16*)alloc((size_t)N * 64 * 2); // -> hact in place
    size_t required = off;

    if (ws_size < required || NB > NBMAX || N >= (1 << 24)) {
        float mb = (float)(double)(ws_size >> 20);
        k_sentinel<<<(out_size + 255) / 256, 256, 0, stream>>>(out, out_size, mb);
        return;
    }

    __hip_bfloat16* h1    = h0;
    __hip_bfloat16* skip1 = h0 + (size_t)N * 32;

    k_probe<<<1, 256, 0, stream>>>((const unsigned*)x, N * 64, (const unsigned*)ei, flags);
    k_params<<<40, 256, 0, stream>>>(flags, d_in[2], d_in[6], d_in[3], d_in[4],
                                     d_in[5], d_in[7], d_in[8], d_in[12],
                                     d_in[9], d_in[10], d_in[11], d_in[13], Pf, Wg);

    int eb = (int)(((long long)E + 4095) / 4096);
    k_zero<<<(NB + 255) / 256, 256, 0, stream>>>(bsize, NB);
    k_bcount<<<eb, 256, 0, stream>>>(ei, flags, E, N, NB, bsize);
    k_bbase<<<1, 1024, 0, stream>>>(bsize, NB, bbase, bcur);
    k_bscatter<<<eb, 1024, 0, stream>>>(ei, flags, E, N, NB, bcur, ebuk);

    k_l0<<<(N + 63) / 64, 256, 0, stream>>>(x, flags, Pf, Wg, N,
                                            h0, skip0, ssrc, sdst);
    k_agg0<<<NB, 256, 0, stream>>>(bbase, bsize, ebuk, ssrc, sdst, h0, N, skip0);
    k_l1<<<(N + 63) / 64, 256, 0, stream>>>(skip0, Pf, Wg, N,
                                            h1, skip1, ssrc, sdst);
    k_agg1<<<NB, 256, 0, stream>>>(bbase, bsize, ebuk, ssrc, sdst, h1, skip1, N, out);
}